// Round 7
// baseline (9871.678 us; speedup 1.0000x reference)
//
#include <hip/hip_runtime.h>

#define Bb 32
#define Tt 512
#define Ee 512
#define Hh 1024

typedef __attribute__((ext_vector_type(8))) short bf16x8;
typedef __attribute__((ext_vector_type(4))) float f32x4;
typedef unsigned long long u64;

__device__ __forceinline__ unsigned short f2bf(float f) {
  unsigned int u = __float_as_uint(f);
  u = (u + 0x7fffu + ((u >> 16) & 1u)) >> 16;
  return (unsigned short)u;
}
__device__ __forceinline__ float bf2f(unsigned short s) {
  return __uint_as_float(((unsigned int)s) << 16);
}
__device__ __forceinline__ float sigmoidf_(float x) {
  x = fminf(fmaxf(x, -30.f), 30.f);
  return 1.f / (1.f + __expf(-x));
}
__device__ __forceinline__ float tanh_fast(float x) {
  float xx = fminf(fmaxf(x, -15.f), 15.f);
  float e = __expf(2.f * xx);
  return (e - 1.f) / (e + 1.f);
}

// Device-scope (LLC) 16B read: bypasses stale L1/L2, reads coherence point.
__device__ __forceinline__ bf16x8 llc_load16(const unsigned short* p) {
  union { u64 q[2]; bf16x8 v; } u;
  const u64* p64 = (const u64*)p;
  u.q[0] = __hip_atomic_load(p64 + 0, __ATOMIC_RELAXED, __HIP_MEMORY_SCOPE_AGENT);
  u.q[1] = __hip_atomic_load(p64 + 1, __ATOMIC_RELAXED, __HIP_MEMORY_SCOPE_AGENT);
  return u.v;
}

// K1: gather embedding rows -> bf16 hi/lo; zero h slots and all flag state.
__global__ void gather_kernel(const int* __restrict__ x,
                              const float* __restrict__ emb,
                              unsigned short* __restrict__ emb_hi,
                              unsigned short* __restrict__ emb_lo,
                              unsigned short* __restrict__ hbuf,
                              unsigned* __restrict__ bar) {
  long long gid = (long long)blockIdx.x * blockDim.x + threadIdx.x;
  long long stride = (long long)gridDim.x * blockDim.x;
  // hbuf: 4 slots x 32x1024 ushorts = 32768 ushort4
  for (long long i = gid; i < 32768; i += stride)
    ((ushort4*)hbuf)[i] = make_ushort4(0, 0, 0, 0);
  for (long long i = gid; i < 1024; i += stride)
    bar[i] = 0u;
  long long n4 = (long long)Bb * Tt * Ee / 4;
  for (long long i = gid; i < n4; i += stride) {
    long long bt = i >> 7;
    int e4 = (int)(i & 127);
    int row = x[bt];
    row = min(max(row, 0), 31999);
    float4 v = ((const float4*)(emb + (long long)row * Ee))[e4];
    ushort4 hv, lv;
    hv.x = f2bf(v.x); lv.x = f2bf(v.x - bf2f(hv.x));
    hv.y = f2bf(v.y); lv.y = f2bf(v.y - bf2f(hv.y));
    hv.z = f2bf(v.z); lv.z = f2bf(v.z - bf2f(hv.z));
    hv.w = f2bf(v.w); lv.w = f2bf(v.w - bf2f(hv.w));
    ((ushort4*)emb_hi)[i] = hv;
    ((ushort4*)emb_lo)[i] = lv;
  }
}

// bar layout (u32):
//   [0..511]    32 global K-group flags, 64B-strided (sc1 atomics — R5-proven)
//   [512..639]  per-(XCD,wave) rf ready flags: 512+xcc*16+wv (PLAIN store/load,
//               single writer, same-L2 visibility only; fallback if unseen)
//   [768..895]  per-XCD relay claim counters (AGENT atomics, one-time)
__global__ __launch_bounds__(256, 1)
void lstm_kernel(const unsigned short* __restrict__ emb_hi,
                 const unsigned short* __restrict__ emb_lo,
                 unsigned short* __restrict__ hbuf,
                 unsigned short* __restrict__ mirror,
                 unsigned* __restrict__ bar,
                 const float* __restrict__ W_ih,
                 const float* __restrict__ W_hh,
                 const float* __restrict__ b_ih,
                 const float* __restrict__ b_hh,
                 float* __restrict__ out) {
  __shared__ unsigned short sWih_hi[16 * 512];
  __shared__ unsigned short sWih_lo[16 * 512];
  __shared__ unsigned short sWhh_hi[16 * 1024];
  __shared__ unsigned short sWhh_lo[16 * 1024];
  __shared__ float sAcc[2][4][2][16][17];
  __shared__ float sBias[16];
  __shared__ float sC[32][4];
  __shared__ int sRelay, sXcc;

  const int tid = threadIdx.x;
  const int lane = tid & 63;
  const int wv = tid >> 6;
  const int wg = blockIdx.x;
  const int j0 = (wg & 7) * 128 + (wg >> 3) * 4;
  const int gflag = (wg & 7) * 4 + (wg >> 6);

  // ---- one-time relay election by PHYSICAL XCD, claim at LLC (agent) ----
  unsigned xcc;
  asm("s_getreg_b32 %0, hwreg(HW_REG_XCC_ID)" : "=s"(xcc));
  if (tid == 0) {
    unsigned c = __hip_atomic_fetch_add(bar + 768 + (xcc & 7) * 16, 1u,
                                        __ATOMIC_RELAXED,
                                        __HIP_MEMORY_SCOPE_AGENT);
    sRelay = (c == 0u) ? 1 : 0;
    sXcc = (int)(xcc & 7);
  }

  // ---- stage W_ih slice (16 rows x 512) hi/lo bf16, XOR-swizzled ----
  for (int idx = tid; idx < 16 * 64; idx += 256) {
    int c = idx >> 6, kc8 = idx & 63;
    int grow = (c >> 2) * Hh + j0 + (c & 3);
    const float* src = W_ih + (long long)grow * Ee + kc8 * 8;
    int us = (c * 512 + kc8 * 8) ^ ((c & 7) << 3);
#pragma unroll
    for (int j = 0; j < 8; j++) {
      float f = src[j];
      unsigned short h = f2bf(f);
      sWih_hi[us + j] = h;
      sWih_lo[us + j] = f2bf(f - bf2f(h));
    }
  }
  // ---- stage W_hh slice (16 rows x 1024) ----
  for (int idx = tid; idx < 16 * 128; idx += 256) {
    int c = idx >> 7, kc8 = idx & 127;
    int grow = (c >> 2) * Hh + j0 + (c & 3);
    const float* src = W_hh + (long long)grow * Hh + kc8 * 8;
    int us = (c * 1024 + kc8 * 8) ^ ((c & 7) << 3);
#pragma unroll
    for (int j = 0; j < 8; j++) {
      float f = src[j];
      unsigned short h = f2bf(f);
      sWhh_hi[us + j] = h;
      sWhh_lo[us + j] = f2bf(f - bf2f(h));
    }
  }
  if (tid < 16) {
    int grow = (tid >> 2) * Hh + j0 + (tid & 3);
    sBias[tid] = b_ih[grow] + b_hh[grow];
  }
  if (tid < 128) sC[tid >> 2][tid & 3] = 0.f;
  __syncthreads();

  const bool isRelay = (sRelay != 0);
  const int myx = sXcc;

  const int r16 = lane & 15;
  const int kg = (lane >> 4) * 8;
  const int col = lane & 15;
  const int xr = (col & 7) << 3;

  const unsigned* fp = bar + (unsigned)(wv + 4 * (lane & 7)) * 16;
  unsigned* rfp = bar + 512 + myx * 16 + wv;

  float h_last = 0.f, c_last = 0.f;
  bool fellback = false;

  for (int t = 0; t < Tt; t++) {
    f32x4 acc[2][3];
#pragma unroll
    for (int mt = 0; mt < 2; mt++)
#pragma unroll
      for (int cb = 0; cb < 3; cb++)
        acc[mt][cb] = (f32x4){0.f, 0.f, 0.f, 0.f};

    // ---- x_proj contribution (independent of h; overlaps all waiting) ----
#pragma unroll
    for (int q = 0; q < 4; q++) {
      int kc = wv + q * 4;
      int bo = (col * 512 + kc * 32 + kg) ^ xr;
      bf16x8 bH = *(const bf16x8*)(sWih_hi + bo);
      bf16x8 bL = *(const bf16x8*)(sWih_lo + bo);
#pragma unroll
      for (int mt = 0; mt < 2; mt++) {
        int rb = mt * 16 + r16;
        int ai = (rb * Tt + t) * Ee + kc * 32 + kg;
        bf16x8 aH = *(const bf16x8*)(emb_hi + ai);
        bf16x8 aL = *(const bf16x8*)(emb_lo + ai);
        acc[mt][0] = __builtin_amdgcn_mfma_f32_16x16x32_bf16(aH, bH, acc[mt][0], 0, 0, 0);
        acc[mt][1] = __builtin_amdgcn_mfma_f32_16x16x32_bf16(aH, bL, acc[mt][1], 0, 0, 0);
        acc[mt][2] = __builtin_amdgcn_mfma_f32_16x16x32_bf16(aL, bH, acc[mt][2], 0, 0, 0);
      }
    }

    unsigned short* mbase =
        mirror + (((unsigned)myx * 4 + (unsigned)(t & 3)) << 15);
    bf16x8 fa0[8], fa1[8];
    bool haveFrags = false;

    if (isRelay) {
      // wait for producers of h[t] at LLC (R5-proven sc1 flag poll)
      unsigned tgt = 16u * (unsigned)t;
      while (__any(__hip_atomic_load(fp, __ATOMIC_RELAXED,
                                     __HIP_MEMORY_SCOPE_AGENT) < tgt))
        __builtin_amdgcn_s_sleep(1);
      // pull h from LLC, stage into this XCD's L2 mirror (plain stores)
      const unsigned short* hb = hbuf + (t & 3) * 32768;
#pragma unroll
      for (int q = 0; q < 8; q++) {
        int kc = wv + q * 4;
        int off0 = r16 * Hh + kc * 32 + kg;
        fa0[q] = llc_load16(hb + off0);
        fa1[q] = llc_load16(hb + 16 * Hh + off0);
        *(bf16x8*)(mbase + off0) = fa0[q];
        *(bf16x8*)(mbase + 16 * Hh + off0) = fa1[q];
      }
      asm volatile("s_waitcnt vmcnt(0)" ::: "memory");  // mirror in L2
      if (lane == 0) *rfp = (unsigned)(t + 1);          // plain store, same L2
      haveFrags = true;
    } else if (!fellback) {
      // poll rf in the shared L2 (sc0 bypasses L0); bounded spin
      unsigned tgt = (unsigned)(t + 1);
      unsigned vv = 0;
      int it = 0;
      do {
        asm volatile("global_load_dword %0, %1, off sc0\n\t"
                     "s_waitcnt vmcnt(0)"
                     : "=v"(vv) : "v"(rfp) : "memory");
        if (vv >= tgt) break;
        __builtin_amdgcn_s_sleep(1);
      } while (++it < 65536);
      if (vv >= tgt) {
        const unsigned short* b0 = mbase + r16 * Hh + wv * 32 + kg;
        const unsigned short* b1 = b0 + 16 * Hh;
        asm volatile(
          "global_load_dwordx4 %0, %16, off sc0\n\t"
          "global_load_dwordx4 %1, %16, off offset:256 sc0\n\t"
          "global_load_dwordx4 %2, %16, off offset:512 sc0\n\t"
          "global_load_dwordx4 %3, %16, off offset:768 sc0\n\t"
          "global_load_dwordx4 %4, %16, off offset:1024 sc0\n\t"
          "global_load_dwordx4 %5, %16, off offset:1280 sc0\n\t"
          "global_load_dwordx4 %6, %16, off offset:1536 sc0\n\t"
          "global_load_dwordx4 %7, %16, off offset:1792 sc0\n\t"
          "global_load_dwordx4 %8, %17, off sc0\n\t"
          "global_load_dwordx4 %9, %17, off offset:256 sc0\n\t"
          "global_load_dwordx4 %10, %17, off offset:512 sc0\n\t"
          "global_load_dwordx4 %11, %17, off offset:768 sc0\n\t"
          "global_load_dwordx4 %12, %17, off offset:1024 sc0\n\t"
          "global_load_dwordx4 %13, %17, off offset:1280 sc0\n\t"
          "global_load_dwordx4 %14, %17, off offset:1536 sc0\n\t"
          "global_load_dwordx4 %15, %17, off offset:1792 sc0\n\t"
          "s_waitcnt vmcnt(0)"
          : "=&v"(fa0[0]), "=&v"(fa0[1]), "=&v"(fa0[2]), "=&v"(fa0[3]),
            "=&v"(fa0[4]), "=&v"(fa0[5]), "=&v"(fa0[6]), "=&v"(fa0[7]),
            "=&v"(fa1[0]), "=&v"(fa1[1]), "=&v"(fa1[2]), "=&v"(fa1[3]),
            "=&v"(fa1[4]), "=&v"(fa1[5]), "=&v"(fa1[6]), "=&v"(fa1[7])
          : "v"(b0), "v"(b1)
          : "memory");
        __builtin_amdgcn_sched_barrier(0);
        haveFrags = true;
      } else {
        fellback = true;   // latch: use LLC path for all remaining steps
      }
    }

    if (!haveFrags) {
      // fallback = R5-proven path: sc1 flag wait + LLC h reads
      unsigned tgt = 16u * (unsigned)t;
      while (__any(__hip_atomic_load(fp, __ATOMIC_RELAXED,
                                     __HIP_MEMORY_SCOPE_AGENT) < tgt))
        __builtin_amdgcn_s_sleep(1);
      const unsigned short* hb = hbuf + (t & 3) * 32768;
#pragma unroll
      for (int q = 0; q < 8; q++) {
        int kc = wv + q * 4;
        int off0 = r16 * Hh + kc * 32 + kg;
        fa0[q] = llc_load16(hb + off0);
        fa1[q] = llc_load16(hb + 16 * Hh + off0);
      }
    }

    // ---- recurrent MFMAs from registers ----
#pragma unroll
    for (int q = 0; q < 8; q++) {
      int kc = wv + q * 4;
      int bo = (col * 1024 + kc * 32 + kg) ^ xr;
      bf16x8 bH = *(const bf16x8*)(sWhh_hi + bo);
      bf16x8 bL = *(const bf16x8*)(sWhh_lo + bo);
      acc[0][0] = __builtin_amdgcn_mfma_f32_16x16x32_bf16(fa0[q], bH, acc[0][0], 0, 0, 0);
      acc[0][1] = __builtin_amdgcn_mfma_f32_16x16x32_bf16(fa0[q], bL, acc[0][1], 0, 0, 0);
      acc[1][0] = __builtin_amdgcn_mfma_f32_16x16x32_bf16(fa1[q], bH, acc[1][0], 0, 0, 0);
      acc[1][1] = __builtin_amdgcn_mfma_f32_16x16x32_bf16(fa1[q], bL, acc[1][1], 0, 0, 0);
    }

    // ---- cross-wave K-split reduction via LDS (parity-double-buffered) ----
#pragma unroll
    for (int mt = 0; mt < 2; mt++) {
      f32x4 tot = acc[mt][0] + acc[mt][1] + acc[mt][2];
#pragma unroll
      for (int r = 0; r < 4; r++)
        sAcc[t & 1][wv][mt][(lane >> 4) * 4 + r][col] = tot[r];
    }
    __syncthreads();

    if (tid < 128) {
      int b = tid >> 2, du = tid & 3;
      int mt = b >> 4, rr = b & 15;
      float g0v = sBias[0 * 4 + du], g1v = sBias[1 * 4 + du];
      float g2v = sBias[2 * 4 + du], g3v = sBias[3 * 4 + du];
#pragma unroll
      for (int w = 0; w < 4; w++) {
        g0v += sAcc[t & 1][w][mt][rr][0 * 4 + du];
        g1v += sAcc[t & 1][w][mt][rr][1 * 4 + du];
        g2v += sAcc[t & 1][w][mt][rr][2 * 4 + du];
        g3v += sAcc[t & 1][w][mt][rr][3 * 4 + du];
      }
      float ig = sigmoidf_(g0v);
      float fg = sigmoidf_(g1v);
      float gg = tanh_fast(g2v);
      float og = sigmoidf_(g3v);
      float cn = fg * sC[b][du] + ig * gg;
      sC[b][du] = cn;
      float hn = og * tanh_fast(cn);
      h_last = hn; c_last = cn;

      unsigned pack = (unsigned)f2bf(hn);
      unsigned other = __shfl_xor(pack, 1, 64);
      unsigned* nb32 = (unsigned*)(hbuf + ((t + 1) & 3) * 32768);
      if ((du & 1) == 0) {
        unsigned w = (pack & 0xffffu) | (other << 16);
        __hip_atomic_store(nb32 + ((b * 1024 + j0 + du) >> 1), w,
                           __ATOMIC_RELAXED, __HIP_MEMORY_SCOPE_AGENT);
      }
      asm volatile("s_waitcnt vmcnt(0)" ::: "memory");
      if ((tid & 63) == 0)
        __hip_atomic_fetch_add(bar + gflag * 16, 1u, __ATOMIC_RELAXED,
                               __HIP_MEMORY_SCOPE_AGENT);
      out[((long long)b * Tt + t) * Hh + j0 + du] = hn;
    }
  }

  if (tid < 128) {
    int b = tid >> 2, du = tid & 3;
    int hj = j0 + du;
    out[16777216LL + b * Hh + hj] = h_last;           // state_h
    out[16777216LL + 32768 + b * Hh + hj] = c_last;   // state_c
  }
}

extern "C" void kernel_launch(void* const* d_in, const int* in_sizes, int n_in,
                              void* d_out, int out_size, void* d_ws, size_t ws_size,
                              hipStream_t stream) {
  const int* x      = (const int*)d_in[0];
  const float* emb  = (const float*)d_in[1];
  const float* W_ih = (const float*)d_in[2];
  const float* W_hh = (const float*)d_in[3];
  const float* b_ih = (const float*)d_in[4];
  const float* b_hh = (const float*)d_in[5];
  float* out = (float*)d_out;

  unsigned short* emb_hi = (unsigned short*)d_ws;       // 16 MB
  unsigned short* emb_lo = emb_hi + 8388608;            // 16 MB
  unsigned short* hbuf   = emb_lo + 8388608;            // 4 slots x 64 KB
  unsigned short* mirror = hbuf + 131072;               // 8 XCD x 4 slots x 64 KB
  unsigned*       bar    = (unsigned*)(mirror + 1048576); // 4 KB flag state

  hipLaunchKernelGGL(gather_kernel, dim3(2048), dim3(256), 0, stream,
                     x, emb, emb_hi, emb_lo, hbuf, bar);

  void* args[] = { (void*)&emb_hi, (void*)&emb_lo, (void*)&hbuf, (void*)&mirror,
                   (void*)&bar, (void*)&W_ih, (void*)&W_hh, (void*)&b_ih,
                   (void*)&b_hh, (void*)&out };
  hipLaunchCooperativeKernel((void*)lstm_kernel, dim3(256), dim3(256), args, 0, stream);
}

// Round 8
// 4717.506 us; speedup vs baseline: 2.0926x; 2.0926x over previous
//
#include <hip/hip_runtime.h>

#define Bb 32
#define Tt 512
#define Ee 512
#define Hh 1024

typedef __attribute__((ext_vector_type(8))) short bf16x8;
typedef __attribute__((ext_vector_type(4))) float f32x4;
typedef unsigned long long u64;

__device__ __forceinline__ unsigned short f2bf(float f) {
  unsigned int u = __float_as_uint(f);
  u = (u + 0x7fffu + ((u >> 16) & 1u)) >> 16;
  return (unsigned short)u;
}
__device__ __forceinline__ float bf2f(unsigned short s) {
  return __uint_as_float(((unsigned int)s) << 16);
}
__device__ __forceinline__ float sigmoidf_(float x) {
  x = fminf(fmaxf(x, -30.f), 30.f);
  return 1.f / (1.f + __expf(-x));
}
__device__ __forceinline__ float tanh_fast(float x) {
  float xx = fminf(fmaxf(x, -15.f), 15.f);
  float e = __expf(2.f * xx);
  return (e - 1.f) / (e + 1.f);
}

// K1: gather embedding rows -> bf16 hi/lo; zero h slots and flag state.
__global__ void gather_kernel(const int* __restrict__ x,
                              const float* __restrict__ emb,
                              unsigned short* __restrict__ emb_hi,
                              unsigned short* __restrict__ emb_lo,
                              unsigned short* __restrict__ hbuf,
                              unsigned* __restrict__ bar) {
  long long gid = (long long)blockIdx.x * blockDim.x + threadIdx.x;
  long long stride = (long long)gridDim.x * blockDim.x;
  // hbuf: 4 slots x 32x1024 ushorts = 32768 ushort4
  for (long long i = gid; i < 32768; i += stride)
    ((ushort4*)hbuf)[i] = make_ushort4(0, 0, 0, 0);
  for (long long i = gid; i < 1024; i += stride)
    bar[i] = 0u;
  long long n4 = (long long)Bb * Tt * Ee / 4;
  for (long long i = gid; i < n4; i += stride) {
    long long bt = i >> 7;
    int e4 = (int)(i & 127);
    int row = x[bt];
    row = min(max(row, 0), 31999);
    float4 v = ((const float4*)(emb + (long long)row * Ee))[e4];
    ushort4 hv, lv;
    hv.x = f2bf(v.x); lv.x = f2bf(v.x - bf2f(hv.x));
    hv.y = f2bf(v.y); lv.y = f2bf(v.y - bf2f(hv.y));
    hv.z = f2bf(v.z); lv.z = f2bf(v.z - bf2f(hv.z));
    hv.w = f2bf(v.w); lv.w = f2bf(v.w - bf2f(hv.w));
    ((ushort4*)emb_hi)[i] = hv;
    ((ushort4*)emb_lo)[i] = lv;
  }
}

// K2: persistent LSTM. 256 WGs; WG owns units j0..j0+3, j0=(wg&7)*128+(wg>>3)*4.
// Producers (R5-proven): sc1 h stores -> vmcnt(0) -> sc1 flag adds (32 flags,
// 64B-strided, +16/flag/step). Consumers (NEW): wave0 polls ALL 32 flags sc1,
// one agent-acquire fence per WG (buffer_inv: L0+L2 clean lines), barrier,
// then PLAIN dwordx4 h loads -> per-XCD L2 amplification of the broadcast.
__global__ __launch_bounds__(256, 1)
void lstm_kernel(const unsigned short* __restrict__ emb_hi,
                 const unsigned short* __restrict__ emb_lo,
                 unsigned short* __restrict__ hbuf,
                 unsigned* __restrict__ bar,
                 const float* __restrict__ W_ih,
                 const float* __restrict__ W_hh,
                 const float* __restrict__ b_ih,
                 const float* __restrict__ b_hh,
                 float* __restrict__ out) {
  __shared__ unsigned short sWih_hi[16 * 512];
  __shared__ unsigned short sWih_lo[16 * 512];
  __shared__ unsigned short sWhh_hi[16 * 1024];
  __shared__ unsigned short sWhh_lo[16 * 1024];
  __shared__ float sAcc[2][4][2][16][17];
  __shared__ float sBias[16];
  __shared__ float sC[32][4];

  const int tid = threadIdx.x;
  const int lane = tid & 63;
  const int wv = tid >> 6;
  const int wg = blockIdx.x;
  const int j0 = (wg & 7) * 128 + (wg >> 3) * 4;
  const int gflag = (wg & 7) * 4 + (wg >> 6);

  // ---- stage W_ih slice (16 rows x 512) hi/lo bf16, XOR-swizzled ----
  for (int idx = tid; idx < 16 * 64; idx += 256) {
    int c = idx >> 6, kc8 = idx & 63;
    int grow = (c >> 2) * Hh + j0 + (c & 3);
    const float* src = W_ih + (long long)grow * Ee + kc8 * 8;
    int us = (c * 512 + kc8 * 8) ^ ((c & 7) << 3);
#pragma unroll
    for (int j = 0; j < 8; j++) {
      float f = src[j];
      unsigned short h = f2bf(f);
      sWih_hi[us + j] = h;
      sWih_lo[us + j] = f2bf(f - bf2f(h));
    }
  }
  // ---- stage W_hh slice (16 rows x 1024) ----
  for (int idx = tid; idx < 16 * 128; idx += 256) {
    int c = idx >> 7, kc8 = idx & 127;
    int grow = (c >> 2) * Hh + j0 + (c & 3);
    const float* src = W_hh + (long long)grow * Hh + kc8 * 8;
    int us = (c * 1024 + kc8 * 8) ^ ((c & 7) << 3);
#pragma unroll
    for (int j = 0; j < 8; j++) {
      float f = src[j];
      unsigned short h = f2bf(f);
      sWhh_hi[us + j] = h;
      sWhh_lo[us + j] = f2bf(f - bf2f(h));
    }
  }
  if (tid < 16) {
    int grow = (tid >> 2) * Hh + j0 + (tid & 3);
    sBias[tid] = b_ih[grow] + b_hh[grow];
  }
  if (tid < 128) sC[tid >> 2][tid & 3] = 0.f;
  __syncthreads();

  const int r16 = lane & 15;        // A-frag row (batch)
  const int kg = (lane >> 4) * 8;   // k-offset in 32-chunk
  const int col = lane & 15;        // B-frag col = gate-slice row
  const int xr = (col & 7) << 3;    // LDS swizzle

  float h_last = 0.f, c_last = 0.f;

  for (int t = 0; t < Tt; t++) {
    f32x4 acc[2][3];
#pragma unroll
    for (int mt = 0; mt < 2; mt++)
#pragma unroll
      for (int cb = 0; cb < 3; cb++)
        acc[mt][cb] = (f32x4){0.f, 0.f, 0.f, 0.f};

    // ---- x_proj contribution (independent of h; overlaps flag wait) ----
#pragma unroll
    for (int q = 0; q < 4; q++) {
      int kc = wv + q * 4;
      int bo = (col * 512 + kc * 32 + kg) ^ xr;
      bf16x8 bH = *(const bf16x8*)(sWih_hi + bo);
      bf16x8 bL = *(const bf16x8*)(sWih_lo + bo);
#pragma unroll
      for (int mt = 0; mt < 2; mt++) {
        int rb = mt * 16 + r16;
        int ai = (rb * Tt + t) * Ee + kc * 32 + kg;
        bf16x8 aH = *(const bf16x8*)(emb_hi + ai);
        bf16x8 aL = *(const bf16x8*)(emb_lo + ai);
        acc[mt][0] = __builtin_amdgcn_mfma_f32_16x16x32_bf16(aH, bH, acc[mt][0], 0, 0, 0);
        acc[mt][1] = __builtin_amdgcn_mfma_f32_16x16x32_bf16(aH, bL, acc[mt][1], 0, 0, 0);
        acc[mt][2] = __builtin_amdgcn_mfma_f32_16x16x32_bf16(aL, bH, acc[mt][2], 0, 0, 0);
      }
    }

    // ---- wave0: wait for ALL 32 K-group flags (h[t] fully at LLC), then
    //      ONE buffer_inv for the whole WG; barrier releases the other waves.
    if (wv == 0) {
      const unsigned* fpl = bar + (unsigned)(lane & 31) * 16;
      unsigned tgt = 16u * (unsigned)t;
      while (__any(__hip_atomic_load(fpl, __ATOMIC_RELAXED,
                                     __HIP_MEMORY_SCOPE_AGENT) < tgt))
        __builtin_amdgcn_s_sleep(1);
      __builtin_amdgcn_fence(__ATOMIC_ACQUIRE, "agent");  // L0+L2 clean-inv
    }
    __syncthreads();

    // ---- recurrent contribution: PLAIN h loads (L2-amplified per XCD) ----
    const unsigned short* hb = hbuf + (t & 3) * 32768;
#pragma unroll
    for (int q = 0; q < 8; q++) {
      int kc = wv + q * 4;
      int bo = (col * 1024 + kc * 32 + kg) ^ xr;
      bf16x8 bH = *(const bf16x8*)(sWhh_hi + bo);
      bf16x8 bL = *(const bf16x8*)(sWhh_lo + bo);
#pragma unroll
      for (int mt = 0; mt < 2; mt++) {
        int rb = mt * 16 + r16;
        bf16x8 aH = *(const bf16x8*)(hb + rb * Hh + kc * 32 + kg);
        acc[mt][0] = __builtin_amdgcn_mfma_f32_16x16x32_bf16(aH, bH, acc[mt][0], 0, 0, 0);
        acc[mt][1] = __builtin_amdgcn_mfma_f32_16x16x32_bf16(aH, bL, acc[mt][1], 0, 0, 0);
      }
    }

    // ---- cross-wave K-split reduction via LDS (parity-double-buffered) ----
#pragma unroll
    for (int mt = 0; mt < 2; mt++) {
      f32x4 tot = acc[mt][0] + acc[mt][1] + acc[mt][2];
#pragma unroll
      for (int r = 0; r < 4; r++)
        sAcc[t & 1][wv][mt][(lane >> 4) * 4 + r][col] = tot[r];
    }
    __syncthreads();

    if (tid < 128) {
      int b = tid >> 2, du = tid & 3;
      int mt = b >> 4, rr = b & 15;
      float g0 = sBias[0 * 4 + du], g1 = sBias[1 * 4 + du];
      float g2 = sBias[2 * 4 + du], g3 = sBias[3 * 4 + du];
#pragma unroll
      for (int w = 0; w < 4; w++) {
        g0 += sAcc[t & 1][w][mt][rr][0 * 4 + du];
        g1 += sAcc[t & 1][w][mt][rr][1 * 4 + du];
        g2 += sAcc[t & 1][w][mt][rr][2 * 4 + du];
        g3 += sAcc[t & 1][w][mt][rr][3 * 4 + du];
      }
      float ig = sigmoidf_(g0);
      float fg = sigmoidf_(g1);
      float gg = tanh_fast(g2);
      float og = sigmoidf_(g3);
      float cn = fg * sC[b][du] + ig * gg;
      sC[b][du] = cn;
      float hn = og * tanh_fast(cn);
      h_last = hn; c_last = cn;

      // h broadcast (single bf16) via sc1 u32 stores, then flag add
      unsigned pack = (unsigned)f2bf(hn);
      unsigned other = __shfl_xor(pack, 1, 64);
      unsigned* nb32 = (unsigned*)(hbuf + ((t + 1) & 3) * 32768);
      if ((du & 1) == 0) {
        unsigned w = (pack & 0xffffu) | (other << 16);
        __hip_atomic_store(nb32 + ((b * 1024 + j0 + du) >> 1), w,
                           __ATOMIC_RELAXED, __HIP_MEMORY_SCOPE_AGENT);
      }
      asm volatile("s_waitcnt vmcnt(0)" ::: "memory");
      if ((tid & 63) == 0)
        __hip_atomic_fetch_add(bar + gflag * 16, 1u, __ATOMIC_RELAXED,
                               __HIP_MEMORY_SCOPE_AGENT);
      out[((long long)b * Tt + t) * Hh + j0 + du] = hn;
    }
  }

  if (tid < 128) {
    int b = tid >> 2, du = tid & 3;
    int hj = j0 + du;
    out[16777216LL + b * Hh + hj] = h_last;           // state_h
    out[16777216LL + 32768 + b * Hh + hj] = c_last;   // state_c
  }
}

extern "C" void kernel_launch(void* const* d_in, const int* in_sizes, int n_in,
                              void* d_out, int out_size, void* d_ws, size_t ws_size,
                              hipStream_t stream) {
  const int* x      = (const int*)d_in[0];
  const float* emb  = (const float*)d_in[1];
  const float* W_ih = (const float*)d_in[2];
  const float* W_hh = (const float*)d_in[3];
  const float* b_ih = (const float*)d_in[4];
  const float* b_hh = (const float*)d_in[5];
  float* out = (float*)d_out;

  unsigned short* emb_hi = (unsigned short*)d_ws;      // 16 MB
  unsigned short* emb_lo = emb_hi + 8388608;           // 16 MB
  unsigned short* hbuf   = emb_lo + 8388608;           // 4 slots x 64 KB
  unsigned*       bar    = (unsigned*)(hbuf + 131072); // 4 KB flag state

  hipLaunchKernelGGL(gather_kernel, dim3(2048), dim3(256), 0, stream,
                     x, emb, emb_hi, emb_lo, hbuf, bar);

  void* args[] = { (void*)&emb_hi, (void*)&emb_lo, (void*)&hbuf, (void*)&bar,
                   (void*)&W_ih, (void*)&W_hh, (void*)&b_ih, (void*)&b_hh,
                   (void*)&out };
  hipLaunchCooperativeKernel((void*)lstm_kernel, dim3(256), dim3(256), args, 0, stream);
}

// Round 9
// 3463.776 us; speedup vs baseline: 2.8500x; 1.3620x over previous
//
#include <hip/hip_runtime.h>

#define Bb 32
#define Tt 512
#define Ee 512
#define Hh 1024
#define NSLOT 256

typedef __attribute__((ext_vector_type(8))) short bf16x8;
typedef __attribute__((ext_vector_type(4))) float f32x4;
typedef unsigned long long u64;

__device__ __forceinline__ unsigned short f2bf(float f) {
  unsigned int u = __float_as_uint(f);
  u = (u + 0x7fffu + ((u >> 16) & 1u)) >> 16;
  return (unsigned short)u;
}
__device__ __forceinline__ float bf2f(unsigned short s) {
  return __uint_as_float(((unsigned int)s) << 16);
}
__device__ __forceinline__ float sigmoidf_(float x) {
  x = fminf(fmaxf(x, -30.f), 30.f);
  return 1.f / (1.f + __expf(-x));
}
__device__ __forceinline__ float tanh_fast(float x) {
  float xx = fminf(fmaxf(x, -15.f), 15.f);
  float e = __expf(2.f * xx);
  return (e - 1.f) / (e + 1.f);
}

// K1: gather embedding rows -> bf16 hi/lo; zero h ring slot 0 + flag state.
__global__ void gather_kernel(const int* __restrict__ x,
                              const float* __restrict__ emb,
                              unsigned short* __restrict__ emb_hi,
                              unsigned short* __restrict__ emb_lo,
                              unsigned short* __restrict__ hbuf,
                              unsigned* __restrict__ bar) {
  long long gid = (long long)blockIdx.x * blockDim.x + threadIdx.x;
  long long stride = (long long)gridDim.x * blockDim.x;
  // slot 0 of the ring: 32x1024 ushorts = 8192 ushort4
  for (long long i = gid; i < 8192; i += stride)
    ((ushort4*)hbuf)[i] = make_ushort4(0, 0, 0, 0);
  for (long long i = gid; i < 1024; i += stride)
    bar[i] = 0u;
  long long n4 = (long long)Bb * Tt * Ee / 4;
  for (long long i = gid; i < n4; i += stride) {
    long long bt = i >> 7;
    int e4 = (int)(i & 127);
    int row = x[bt];
    row = min(max(row, 0), 31999);
    float4 v = ((const float4*)(emb + (long long)row * Ee))[e4];
    ushort4 hv, lv;
    hv.x = f2bf(v.x); lv.x = f2bf(v.x - bf2f(hv.x));
    hv.y = f2bf(v.y); lv.y = f2bf(v.y - bf2f(hv.y));
    hv.z = f2bf(v.z); lv.z = f2bf(v.z - bf2f(hv.z));
    hv.w = f2bf(v.w); lv.w = f2bf(v.w - bf2f(hv.w));
    ((ushort4*)emb_hi)[i] = hv;
    ((ushort4*)emb_lo)[i] = lv;
  }
}

// K2: persistent LSTM. 256 WGs; WG owns units j0..j0+3, j0=(wg&7)*128+(wg>>3)*4.
// Publish (R5-proven): sc1 h stores -> vmcnt(0) -> sc1 flag adds (32 flags).
// Consume (NEW): per-wave sc1 poll of its 8 flags, then PLAIN dwordx4 loads
// from a 256-slot rotating ring — every line is touched for the FIRST time
// after the flag, so demand fills are coherent with zero fences/invs, and
// per-XCD L2 amplifies the broadcast (2 MB -> 64 KB fabric per XCD per step).
__global__ __launch_bounds__(256, 1)
void lstm_kernel(const unsigned short* __restrict__ emb_hi,
                 const unsigned short* __restrict__ emb_lo,
                 unsigned short* __restrict__ hbuf,
                 unsigned* __restrict__ bar,
                 const float* __restrict__ W_ih,
                 const float* __restrict__ W_hh,
                 const float* __restrict__ b_ih,
                 const float* __restrict__ b_hh,
                 float* __restrict__ out) {
  __shared__ unsigned short sWih_hi[16 * 512];
  __shared__ unsigned short sWih_lo[16 * 512];
  __shared__ unsigned short sWhh_hi[16 * 1024];
  __shared__ unsigned short sWhh_lo[16 * 1024];
  __shared__ float sAcc[2][4][2][16][17];
  __shared__ float sBias[16];
  __shared__ float sC[32][4];

  const int tid = threadIdx.x;
  const int lane = tid & 63;
  const int wv = tid >> 6;
  const int wg = blockIdx.x;
  const int j0 = (wg & 7) * 128 + (wg >> 3) * 4;
  const int gflag = (wg & 7) * 4 + (wg >> 6);

  // ---- stage W_ih slice (16 rows x 512) hi/lo bf16, XOR-swizzled ----
  for (int idx = tid; idx < 16 * 64; idx += 256) {
    int c = idx >> 6, kc8 = idx & 63;
    int grow = (c >> 2) * Hh + j0 + (c & 3);
    const float* src = W_ih + (long long)grow * Ee + kc8 * 8;
    int us = (c * 512 + kc8 * 8) ^ ((c & 7) << 3);
#pragma unroll
    for (int j = 0; j < 8; j++) {
      float f = src[j];
      unsigned short h = f2bf(f);
      sWih_hi[us + j] = h;
      sWih_lo[us + j] = f2bf(f - bf2f(h));
    }
  }
  // ---- stage W_hh slice (16 rows x 1024) ----
  for (int idx = tid; idx < 16 * 128; idx += 256) {
    int c = idx >> 7, kc8 = idx & 127;
    int grow = (c >> 2) * Hh + j0 + (c & 3);
    const float* src = W_hh + (long long)grow * Hh + kc8 * 8;
    int us = (c * 1024 + kc8 * 8) ^ ((c & 7) << 3);
#pragma unroll
    for (int j = 0; j < 8; j++) {
      float f = src[j];
      unsigned short h = f2bf(f);
      sWhh_hi[us + j] = h;
      sWhh_lo[us + j] = f2bf(f - bf2f(h));
    }
  }
  if (tid < 16) {
    int grow = (tid >> 2) * Hh + j0 + (tid & 3);
    sBias[tid] = b_ih[grow] + b_hh[grow];
  }
  if (tid < 128) sC[tid >> 2][tid & 3] = 0.f;
  __syncthreads();

  const int r16 = lane & 15;        // A-frag row (batch)
  const int kg = (lane >> 4) * 8;   // k-offset in 32-chunk
  const int col = lane & 15;        // B-frag col = gate-slice row
  const int xr = (col & 7) << 3;    // LDS swizzle

  // this wave's 8 flag pointers (lanes 0..7 distinct, others duplicate)
  const unsigned* fp = bar + (unsigned)(wv + 4 * (lane & 7)) * 16;

  float h_last = 0.f, c_last = 0.f;

  for (int t = 0; t < Tt; t++) {
    f32x4 acc[2][3];
#pragma unroll
    for (int mt = 0; mt < 2; mt++)
#pragma unroll
      for (int cb = 0; cb < 3; cb++)
        acc[mt][cb] = (f32x4){0.f, 0.f, 0.f, 0.f};

    // ---- x_proj contribution (independent of h; overlaps flag wait) ----
#pragma unroll
    for (int q = 0; q < 4; q++) {
      int kc = wv + q * 4;
      int bo = (col * 512 + kc * 32 + kg) ^ xr;
      bf16x8 bH = *(const bf16x8*)(sWih_hi + bo);
      bf16x8 bL = *(const bf16x8*)(sWih_lo + bo);
#pragma unroll
      for (int mt = 0; mt < 2; mt++) {
        int rb = mt * 16 + r16;
        int ai = (rb * Tt + t) * Ee + kc * 32 + kg;
        bf16x8 aH = *(const bf16x8*)(emb_hi + ai);
        bf16x8 aL = *(const bf16x8*)(emb_lo + ai);
        acc[mt][0] = __builtin_amdgcn_mfma_f32_16x16x32_bf16(aH, bH, acc[mt][0], 0, 0, 0);
        acc[mt][1] = __builtin_amdgcn_mfma_f32_16x16x32_bf16(aH, bL, acc[mt][1], 0, 0, 0);
        acc[mt][2] = __builtin_amdgcn_mfma_f32_16x16x32_bf16(aL, bH, acc[mt][2], 0, 0, 0);
      }
    }

    // ---- per-wave wait: this wave's 8 K-groups published for step t ----
    {
      unsigned target = 16u * (unsigned)t;
      while (__any(__hip_atomic_load(fp, __ATOMIC_RELAXED,
                                     __HIP_MEMORY_SCOPE_AGENT) < target))
        __builtin_amdgcn_s_sleep(1);
    }
    __builtin_amdgcn_sched_barrier(0);   // keep h loads below the poll

    // ---- recurrent contribution: PLAIN loads from cold ring slot ----
    const unsigned short* hb = hbuf + (unsigned)(t & (NSLOT - 1)) * 32768;
#pragma unroll
    for (int q = 0; q < 8; q++) {
      int kc = wv + q * 4;
      int bo = (col * 1024 + kc * 32 + kg) ^ xr;
      bf16x8 bH = *(const bf16x8*)(sWhh_hi + bo);
      bf16x8 bL = *(const bf16x8*)(sWhh_lo + bo);
#pragma unroll
      for (int mt = 0; mt < 2; mt++) {
        int rb = mt * 16 + r16;
        bf16x8 aH = *(const bf16x8*)(hb + rb * Hh + kc * 32 + kg);
        acc[mt][0] = __builtin_amdgcn_mfma_f32_16x16x32_bf16(aH, bH, acc[mt][0], 0, 0, 0);
        acc[mt][1] = __builtin_amdgcn_mfma_f32_16x16x32_bf16(aH, bL, acc[mt][1], 0, 0, 0);
      }
    }

    // ---- cross-wave K-split reduction via LDS (parity-double-buffered) ----
#pragma unroll
    for (int mt = 0; mt < 2; mt++) {
      f32x4 tot = acc[mt][0] + acc[mt][1] + acc[mt][2];
#pragma unroll
      for (int r = 0; r < 4; r++)
        sAcc[t & 1][wv][mt][(lane >> 4) * 4 + r][col] = tot[r];
    }
    __syncthreads();

    if (tid < 128) {
      int b = tid >> 2, du = tid & 3;
      int mt = b >> 4, rr = b & 15;
      float g0 = sBias[0 * 4 + du], g1 = sBias[1 * 4 + du];
      float g2 = sBias[2 * 4 + du], g3 = sBias[3 * 4 + du];
#pragma unroll
      for (int w = 0; w < 4; w++) {
        g0 += sAcc[t & 1][w][mt][rr][0 * 4 + du];
        g1 += sAcc[t & 1][w][mt][rr][1 * 4 + du];
        g2 += sAcc[t & 1][w][mt][rr][2 * 4 + du];
        g3 += sAcc[t & 1][w][mt][rr][3 * 4 + du];
      }
      float ig = sigmoidf_(g0);
      float fg = sigmoidf_(g1);
      float gg = tanh_fast(g2);
      float og = sigmoidf_(g3);
      float cn = fg * sC[b][du] + ig * gg;
      sC[b][du] = cn;
      float hn = og * tanh_fast(cn);
      h_last = hn; c_last = cn;

      // publish h (single bf16) into ring slot t+1 via sc1 u32 stores
      unsigned pack = (unsigned)f2bf(hn);
      unsigned other = __shfl_xor(pack, 1, 64);
      unsigned* nb32 =
          (unsigned*)(hbuf + (unsigned)((t + 1) & (NSLOT - 1)) * 32768);
      if ((du & 1) == 0) {
        unsigned w = (pack & 0xffffu) | (other << 16);
        __hip_atomic_store(nb32 + ((b * 1024 + j0 + du) >> 1), w,
                           __ATOMIC_RELAXED, __HIP_MEMORY_SCOPE_AGENT);
      }
      asm volatile("s_waitcnt vmcnt(0)" ::: "memory");
      if ((tid & 63) == 0)
        __hip_atomic_fetch_add(bar + gflag * 16, 1u, __ATOMIC_RELAXED,
                               __HIP_MEMORY_SCOPE_AGENT);
      out[((long long)b * Tt + t) * Hh + j0 + du] = hn;
    }
    // no tail barrier: sAcc parity-buffered; ring reuse distance = 256 steps
  }

  if (tid < 128) {
    int b = tid >> 2, du = tid & 3;
    int hj = j0 + du;
    out[16777216LL + b * Hh + hj] = h_last;           // state_h
    out[16777216LL + 32768 + b * Hh + hj] = c_last;   // state_c
  }
}

extern "C" void kernel_launch(void* const* d_in, const int* in_sizes, int n_in,
                              void* d_out, int out_size, void* d_ws, size_t ws_size,
                              hipStream_t stream) {
  const int* x      = (const int*)d_in[0];
  const float* emb  = (const float*)d_in[1];
  const float* W_ih = (const float*)d_in[2];
  const float* W_hh = (const float*)d_in[3];
  const float* b_ih = (const float*)d_in[4];
  const float* b_hh = (const float*)d_in[5];
  float* out = (float*)d_out;

  unsigned short* emb_hi = (unsigned short*)d_ws;      // 16 MB
  unsigned short* emb_lo = emb_hi + 8388608;           // 16 MB
  unsigned short* hbuf   = emb_lo + 8388608;           // 256-slot ring, 16 MB
  unsigned*       bar    = (unsigned*)(hbuf + 8388608); // 4 KB flag state

  hipLaunchKernelGGL(gather_kernel, dim3(2048), dim3(256), 0, stream,
                     x, emb, emb_hi, emb_lo, hbuf, bar);

  void* args[] = { (void*)&emb_hi, (void*)&emb_lo, (void*)&hbuf, (void*)&bar,
                   (void*)&W_ih, (void*)&W_hh, (void*)&b_ih, (void*)&b_hh,
                   (void*)&out };
  hipLaunchCooperativeKernel((void*)lstm_kernel, dim3(256), dim3(256), args, 0, stream);
}